// Round 1
// baseline (259.260 us; speedup 1.0000x reference)
//
#include <hip/hip_runtime.h>
#include <hip/hip_bf16.h>

#define AS1 __attribute__((address_space(1)))
#define AS3 __attribute__((address_space(3)))

typedef unsigned short u16;
typedef short bf16x8 __attribute__((ext_vector_type(8)));
typedef unsigned short u16x8 __attribute__((ext_vector_type(8)));
typedef float f32x4 __attribute__((ext_vector_type(4)));

#define MFMA16 __builtin_amdgcn_mfma_f32_16x16x32_bf16

#define SBAR()  asm volatile("s_barrier" ::: "memory")
#define WAITV(N) asm volatile("s_waitcnt vmcnt(" #N ")" ::: "memory")
#define WAITL0() asm volatile("s_waitcnt lgkmcnt(0)" ::: "memory")

// ---------------- helpers ----------------

__device__ __forceinline__ u16 f2bf(float f) {        // RNE (finite data)
  union { float f; unsigned u; } c; c.f = f;
  unsigned u = c.u;
  u = u + 0x7fffu + ((u >> 16) & 1u);
  return (u16)(u >> 16);
}

__device__ __forceinline__ float fexp2(float x) {
#if __has_builtin(__builtin_amdgcn_exp2f)
  return __builtin_amdgcn_exp2f(x);
#else
  return exp2f(x);
#endif
}

// pack bf16(a) low16, bf16(b) high16 (truncating) — 1 v_perm_b32
__device__ __forceinline__ unsigned pack_bf(float a, float b) {
  union { float f; unsigned u; } ua, ub; ua.f = a; ub.f = b;
  return __builtin_amdgcn_perm(ub.u, ua.u, 0x07060302u);
}

__device__ __forceinline__ void gl_lds16(const void* g, void* l) {
  __builtin_amdgcn_global_load_lds((const AS1 void*)g, (AS3 void*)l, 16, 0, 0);
}

// ---------------- cast fp32 -> bf16, with 64-col-tile granule swizzle ----------------

__global__ void cast_all_kernel(const float* __restrict__ x,
                                const float* __restrict__ wqkv,
                                const float* __restrict__ wout,
                                u16* __restrict__ ws) {
  int i = blockIdx.x * blockDim.x + threadIdx.x;   // float4 index, 3145728 total
  const float4* src;
  int rel;
  size_t matbase;
  if (i < 2097152)      { src = (const float4*)x + i;                rel = i;           matbase = 0; }
  else if (i < 2883584) { src = (const float4*)wqkv + (i - 2097152); rel = i - 2097152; matbase = 8388608; }
  else                  { src = (const float4*)wout + (i - 2883584); rel = i - 2883584; matbase = 11534336; }
  float4 f = *src;
  ushort4 o;
  o.x = f2bf(f.x); o.y = f2bf(f.y); o.z = f2bf(f.z); o.w = f2bf(f.w);
  int fe  = rel * 4;
  int row = fe >> 10, c = fe & 1023;
  int newc = (c & ~63) | (((((c >> 3) ^ row) & 7) << 3)) | (c & 7);
  ((ushort4*)ws)[(matbase + (size_t)row * 1024 + newc) >> 2] = o;
}

// ---------------- GEMM: C[M,N] = A[M,K] * B[N,K]^T  (bf16 in, fp32 acc) ----------------
// 256x128 tile, 8 waves (2M x 4N), BK=64, 4-phase pipelined schedule:
//   phase A: ds_read kk1 frags      | MFMA Q1 (mh0 x kk0, pre-read)        | s_barrier
//   phase B: (reads done)           | MFMA Q2 (mh1 x kk0); lgkmcnt(0)      | s_barrier  -> buf free
//   phase C: stage A-h0+B of kt+2   | MFMA Q3 (mh0 x kk1); vmcnt(4) gate   | s_barrier
//   phase D: stage A-h1 of kt+2     | ds_read kt+1 kk0; MFMA Q4 (mh1 kk1)  | s_barrier
// Counted vmcnt only (never 0 mid-loop); raw s_barrier (no drain); setprio around MFMA.

template<int EPI>
__global__ __launch_bounds__(512, 2) void gemm_bt2(
    const u16* __restrict__ A, const u16* __restrict__ Bm,
    float* __restrict__ Cf,
    u16* __restrict__ qd, u16* __restrict__ kd, u16* __restrict__ vd,
    int M, int N, int K)
{
  __shared__ u16 As[2][2][128 * 64];   // [buf][half][row*64+col]  64 KB
  __shared__ u16 Bs[2][128 * 64];      // [buf][row*64+col]        32 KB

  const int tid  = threadIdx.x;
  const int wave = tid >> 6, lane = tid & 63;
  const int quad = lane >> 4, l16 = lane & 15;

  // bijective XCD-aware swizzle (grid count is a multiple of 8)
  const int gx  = gridDim.x;
  const int nwg = gx * gridDim.y;
  const int lin = blockIdx.y * gx + blockIdx.x;
  const int q8  = nwg >> 3;
  const int swz = (lin & 7) * q8 + (lin >> 3);
  const int bm = (swz / gx) * 256;
  const int bn = (swz % gx) * 128;

  const int hA = wave >> 2;            // which A half this wave consumes
  const int wn = (wave & 3) * 32;

  // staging addresses: thread covers row (tid>>3), cols (tid&7)*8..+7
  const int srow = tid >> 3;           // 0..63
  const int scol = (tid & 7) * 8;
  const u16* Ab = A  + (size_t)(bm + srow) * K + scol;
  const u16* Bb = Bm + (size_t)(bn + srow) * K + scol;
  const int ldsw = wave * 512;         // wave-uniform LDS base (elems) inside a half

  const int NT = K >> 6;

  auto stA = [&](int t, int h) {       // one A half-tile: 2 x global_load_lds
    int d = t & 1;
    #pragma unroll
    for (int i = 0; i < 2; ++i)
      gl_lds16(Ab + (size_t)(128 * h + 64 * i) * K + t * 64,
               &As[d][h][ldsw + i * 4096]);
  };
  auto stB = [&](int t) {              // B tile: 2 x global_load_lds
    int d = t & 1;
    #pragma unroll
    for (int i = 0; i < 2; ++i)
      gl_lds16(Bb + (size_t)(64 * i) * K + t * 64,
               &Bs[d][ldsw + i * 4096]);
  };
  auto rdA = [&](int d, int mf, int g) -> bf16x8 {
    int row = mf * 16 + l16;
    return *(const bf16x8*)&As[d][hA][row * 64 + (((g ^ row) & 7) << 3)];
  };
  auto rdB = [&](int d, int nf, int g) -> bf16x8 {
    int row = wn + nf * 16 + l16;
    return *(const bf16x8*)&Bs[d][row * 64 + (((g ^ row) & 7) << 3)];
  };

  f32x4 acc[8][2] = {};
  bf16x8 fa0[8], fb0[2];   // current tile, kk=0 frags
  bf16x8 fa1[8], fb1[2];   // current tile, kk=32 frags

  // ---- prologue: stage tiles 0 and 1; wait tile 0; pre-read tile 0 kk0 ----
  stA(0, 0); stA(0, 1); stB(0);
  stA(1, 0); stA(1, 1); stB(1);
  WAITV(6);
  SBAR();
  #pragma unroll
  for (int mf = 0; mf < 8; ++mf) fa0[mf] = rdA(0, mf, quad);
  fb0[0] = rdB(0, 0, quad); fb0[1] = rdB(0, 1, quad);

  for (int kt = 0; kt < NT; ++kt) {
    const int dd = kt & 1;

    // ---- phase A: read kk1 frags; MFMA Q1 (mf0-3 x kk0) ----
    #pragma unroll
    for (int mf = 0; mf < 8; ++mf) fa1[mf] = rdA(dd, mf, quad + 4);
    fb1[0] = rdB(dd, 0, quad + 4); fb1[1] = rdB(dd, 1, quad + 4);
    __builtin_amdgcn_s_setprio(1);
    #pragma unroll
    for (int mf = 0; mf < 4; ++mf) {
      acc[mf][0] = MFMA16(fa0[mf], fb0[0], acc[mf][0], 0, 0, 0);
      acc[mf][1] = MFMA16(fa0[mf], fb0[1], acc[mf][1], 0, 0, 0);
    }
    __builtin_amdgcn_s_setprio(0);
    SBAR();

    // ---- phase B: MFMA Q2 (mf4-7 x kk0); all reads of buf dd drained ----
    __builtin_amdgcn_s_setprio(1);
    #pragma unroll
    for (int mf = 4; mf < 8; ++mf) {
      acc[mf][0] = MFMA16(fa0[mf], fb0[0], acc[mf][0], 0, 0, 0);
      acc[mf][1] = MFMA16(fa0[mf], fb0[1], acc[mf][1], 0, 0, 0);
    }
    __builtin_amdgcn_s_setprio(0);
    WAITL0();                          // my ds_reads of buf dd complete
    __builtin_amdgcn_sched_barrier(0);
    SBAR();                            // all waves done reading -> buf dd free

    // ---- phase C: stage A-h0 + B of tile kt+2; MFMA Q3 (mf0-3 x kk1); gate kt+1 ----
    if (kt + 2 < NT) { stA(kt + 2, 0); stB(kt + 2); }
    __builtin_amdgcn_s_setprio(1);
    #pragma unroll
    for (int mf = 0; mf < 4; ++mf) {
      acc[mf][0] = MFMA16(fa1[mf], fb1[0], acc[mf][0], 0, 0, 0);
      acc[mf][1] = MFMA16(fa1[mf], fb1[1], acc[mf][1], 0, 0, 0);
    }
    __builtin_amdgcn_s_setprio(0);
    if (kt + 1 < NT) {
      if (kt + 2 < NT) { WAITV(4); }   // tile kt+1 complete; kt+2's 4 loads stay in flight
      else             { WAITV(0); }   // epilogue drain (last gate only)
    }
    SBAR();

    // ---- phase D: stage A-h1 of kt+2; pre-read tile kt+1 kk0; MFMA Q4 (mf4-7 x kk1) ----
    if (kt + 2 < NT) stA(kt + 2, 1);
    if (kt + 1 < NT) {
      const int dn = (kt + 1) & 1;
      #pragma unroll
      for (int mf = 0; mf < 8; ++mf) fa0[mf] = rdA(dn, mf, quad);
      fb0[0] = rdB(dn, 0, quad); fb0[1] = rdB(dn, 1, quad);
    }
    __builtin_amdgcn_s_setprio(1);
    #pragma unroll
    for (int mf = 4; mf < 8; ++mf) {
      acc[mf][0] = MFMA16(fa1[mf], fb1[0], acc[mf][0], 0, 0, 0);
      acc[mf][1] = MFMA16(fa1[mf], fb1[1], acc[mf][1], 0, 0, 0);
    }
    __builtin_amdgcn_s_setprio(0);
    SBAR();
  }

  // ---- epilogue ----
  #pragma unroll
  for (int mf = 0; mf < 8; ++mf) {
    #pragma unroll
    for (int nf = 0; nf < 2; ++nf) {
      #pragma unroll
      for (int r = 0; r < 4; ++r) {
        int m = bm + hA * 128 + mf * 16 + quad * 4 + r;
        int n = bn + wn + nf * 16 + l16;
        float val = acc[mf][nf][r];
        if (EPI == 0) {
          Cf[(size_t)m * N + n] = val;
        } else {
          int part = n >> 10, rem = n & 1023;
          int h = rem >> 6, dcol = rem & 63;
          int b = m >> 12, s = m & 4095;
          if (part == 0) val *= 0.1803368801111244f;   // 0.125 * log2(e), exp2 path
          u16* dst = (part == 0) ? qd : (part == 1) ? kd : vd;
          dst[((size_t)((b * 16 + h) * 4096 + s)) * 64 + dcol] = f2bf(val);
        }
      }
    }
  }
}

// ---------------- V pack: [B,H,S,64] -> operand-order [B,H, tile(64), jd(4), h(2), lane(64), 8] ----

__global__ __launch_bounds__(256) void pack_v(const u16* __restrict__ vb,
                                              u16* __restrict__ vt) {
  __shared__ u16 Lt[64 * 72];
  const int tid = threadIdx.x, bid = blockIdx.x;
  const int bh = bid & 31, t = bid >> 5;
  const size_t base = (size_t)bh << 18;
  #pragma unroll
  for (int c = 0; c < 2; ++c) {
    int idx = tid * 8 + c * 2048;
    int row = idx >> 6, col = idx & 63;                 // row=key, col=dh
    u16x8 vv = *(const u16x8*)&vb[base + (size_t)(t * 64 + row) * 64 + col];
    #pragma unroll
    for (int s = 0; s < 8; ++s) Lt[(col + s) * 72 + row] = vv[s];
  }
  __syncthreads();
  #pragma unroll
  for (int c = 0; c < 2; ++c) {
    int w = tid + c * 256;                              // 512 chunks
    int dh = w >> 3, k8 = w & 7;
    u16x8 o;
    #pragma unroll
    for (int s = 0; s < 8; ++s) o[s] = Lt[dh * 72 + k8 * 8 + s];
    int off = ((dh >> 4) << 10) | ((k8 >> 2) << 9) | ((k8 & 3) << 7) | ((dh & 15) << 3);
    *(u16x8*)&vt[base + (size_t)t * 4096 + off] = o;
  }
}

// ---------------- attention: 4 independent waves/block, S^T trick, coalesced V ----------------

__global__ __launch_bounds__(256) void attn_kernel(
    const u16* __restrict__ qb, const u16* __restrict__ kb,
    const u16* __restrict__ vt, u16* __restrict__ ob)
{
  __shared__ u16 Ps[4][32 * 64];

  const int tid  = threadIdx.x;
  const int wave = tid >> 6;
  const int lane = tid & 63;
  const int quad = lane >> 4, l16 = lane & 15;
  const int bid  = blockIdx.x;
  const int bh   = bid & 31;
  const int t0   = (((bid >> 5) << 2) | wave) << 5;
  const size_t base = (size_t)bh << 18;
  u16* __restrict__ ps = &Ps[wave][0];

  const int l64 = l16 * 64 + quad * 8;
  const u16* vbase = vt + base + lane * 8;   // + tile*4096 + jd*1024 + h*512

  // Q B-fragments (B[n=query l16][k=dh]); q pre-scaled by 0.125*log2e
  const u16* qp = qb + base + (size_t)t0 * 64 + l64;
  bf16x8 bq00 = *(const bf16x8*)(qp);
  bf16x8 bq01 = *(const bf16x8*)(qp + 32);
  bf16x8 bq10 = *(const bf16x8*)(qp + 1024);
  bf16x8 bq11 = *(const bf16x8*)(qp + 1056);

  f32x4 oacc[2][4] = {};
  f32x4 lacc[2] = {};
  bf16x8 ones;
  #pragma unroll
  for (int s = 0; s < 8; ++s) ones[s] = (short)0x3F80;

  const int lo = max(0, t0 - 511) >> 6;
  const int hi = (t0 + 31) >> 6;

  auto loadK = [&](int kb0, bf16x8 (&kf)[4][2]) {
    #pragma unroll
    for (int j = 0; j < 4; ++j) {
      const u16* krow = kb + base + (size_t)(kb0 + j * 16) * 64 + l64;
      kf[j][0] = *(const bf16x8*)(krow);
      kf[j][1] = *(const bf16x8*)(krow + 32);
    }
  };

  bf16x8 ka[4][2], kb2[4][2];

  // ======== prefix tile (keys 0..15 causal; keys 16..31 zero-filled) ========
  {
    const u16* kpre = kb + base + l64;
    bf16x8 pk0 = *(const bf16x8*)(kpre);
    bf16x8 pk1 = *(const bf16x8*)(kpre + 32);
    loadK(lo << 6, ka);                        // prefetch first window tile
    bf16x8 pv[4];
    #pragma unroll
    for (int jd = 0; jd < 4; ++jd)
      pv[jd] = *(const bf16x8*)(vbase + jd * 1024);   // tile 0, h=0

    #pragma unroll
    for (int i = 0; i < 2; ++i) {
      f32x4 t4 = {};
      t4 = MFMA16(pk0, i ? bq10 : bq00, t4, 0, 0, 0);
      t4 = MFMA16(pk1, i ? bq11 : bq01, t4, 0, 0, 0);
      int row = i * 16 + l16;
      int qpos = t0 + row;
      float p[4];
      #pragma unroll
      for (int r = 0; r < 4; ++r) {
        int kpos = quad * 4 + r;
        p[r] = (kpos <= qpos) ? fexp2(t4[r]) : 0.f;
      }
      uint2 w;
      w.x = pack_bf(p[0], p[1]);
      w.y = pack_bf(p[2], p[3]);
      *(uint2*)&ps[row * 64 + ((quad ^ l16) & 15) * 4] = w;
      uint2 z; z.x = 0u; z.y = 0u;
      *(uint2*)&ps[row * 64 + (((4 + quad) ^ l16) & 15) * 4] = z;
    }
    #pragma unroll
    for (int i = 0; i < 2; ++i) {
      int row = i * 16 + l16;
      uint2 r0 = *(uint2*)&ps[row * 64 + (((2 * quad) ^ l16) & 15) * 4];
      uint2 r1 = *(uint2*)&ps[row * 64 + (((2 * quad + 1) ^ l16) & 15) * 4];
      union { uint4 u; bf16x8 v; } cc; cc.u = make_uint4(r0.x, r0.y, r1.x, r1.y);
      bf16x8 ap = cc.v;
      lacc[i] = MFMA16(ap, ones, lacc[i], 0, 0, 0);
      #pragma unroll
      for (int jd = 0; jd < 4; ++jd)
        oacc[i][jd] = MFMA16(ap, pv[jd], oacc[i][jd], 0, 0, 0);
    }
  }

  // ======== sliding-window tiles ========
  auto tilec = [&](int kb0, bf16x8 (&kf)[4][2]) {
    #pragma unroll
    for (int j = 0; j < 4; ++j) {
      const int kmin = kb0 + j * 16;
      #pragma unroll
      for (int i = 0; i < 2; ++i) {
        const int qmin = t0 + i * 16;
        const int row  = i * 16 + l16;
        uint2* dst = (uint2*)&ps[row * 64 + (((j * 4 + quad) ^ l16) & 15) * 4];
        // wave-uniform subtile classification
        const bool sub_masked = (kmin > qmin + 15) || (qmin - kmin >= 527) || (kmin < 16);
        if (sub_masked) { uint2 z; z.x = 0u; z.y = 0u; *dst = z; continue; }
        f32x4 t4 = {};
        t4 = MFMA16(kf[j][0], i ? bq10 : bq00, t4, 0, 0, 0);
        t4 = MFMA16(kf[j][1], i ? bq11 : bq01, t4, 0, 0, 0);
        const bool sub_ok = (kmin + 15 <= qmin) && (qmin + 15 - kmin < 512);
        float p[4];
        if (sub_ok) {
          #pragma unroll
          for (int r = 0; r < 4; ++r) p[r] = fexp2(t4[r]);
        } else {
          int qpos = t0 + row;
          #pragma unroll
          for (int r = 0; r < 4; ++r) {
            int kpos = kmin + quad * 4 + r;       // kmin >= 16 guaranteed here
            unsigned diff = (unsigned)(qpos - kpos);
            p[r] = (diff < 512u) ? fexp2(t4[r]) : 0.f;
          }
        }
        uint2 w;
        w.x = pack_bf(p[0], p[1]);
        w.y = pack_bf(p[2], p[3]);
        *dst = w;
      }
    }
    // PV + l accumulation; V frags contiguous 1KB each, reused across i
    const u16* vp = vbase + (size_t)kb0 * 64;
    #pragma unroll
    for (int h = 0; h < 2; ++h) {
      bf16x8 bv0 = *(const bf16x8*)(vp + h * 512);
      bf16x8 bv1 = *(const bf16x8*)(vp + 1024 + h * 512);
      bf16x8 bv2 = *(const bf16x8*)(vp + 2048 + h * 512);
      bf16x8 bv3 = *(const bf16x8*)(vp + 3072 + h * 512);
      #pragma unroll
      for (int i = 0; i < 2; ++i) {
        int row = i * 16 + l16;
        int g0 = h * 8 + 2 * quad;
        uint2 r0 = *(uint2*)&ps[row * 64 + ((g0 ^ l16) & 15) * 4];
        uint2 r1 = *(uint2*)&ps[row * 64 + (((g0 + 1) ^ l16) & 15) * 4];
        union { uint4 u; bf16x8 v; } cc; cc.u = make_uint4(r0.x, r0.y, r1.x, r1.y);
        bf16x8 ap = cc.v;
        lacc[i] = MFMA16(ap, ones, lacc[i], 0, 0, 0);
        oacc[i][0] = MFMA16(ap, bv0, oacc[i][0], 0, 0, 0);
        oacc[i][1] = MFMA16(ap, bv1, oacc[i][1], 0, 0, 0);
        oacc[i][2] = MFMA16(ap, bv2, oacc[i][2], 0, 0, 0);
        oacc[i][3] = MFMA16(ap, bv3, oacc[i][3], 0, 0, 0);
      }
    }
  };

  for (int t = lo; t <= hi; t += 2) {
    if (t + 1 <= hi) loadK((t + 1) << 6, kb2);
    tilec(t << 6, ka);
    if (t + 1 <= hi) {
      if (t + 2 <= hi) loadK((t + 2) << 6, ka);
      tilec((t + 1) << 6, kb2);
    }
  }

  // ---- epilogue: O/l -> bf16 [B,S,H*64], granule-swizzled for GEMM3 staging ----
  const int b = bh >> 4, h = bh & 15;
  #pragma unroll
  for (int i = 0; i < 2; ++i) {
    #pragma unroll
    for (int r = 0; r < 4; ++r) {
      float inv = 1.f / lacc[i][r];
      int srow = t0 + i * 16 + quad * 4 + r;
      size_t rowoff = ((size_t)(b * 4096 + srow)) * 1024 + h * 64;
      #pragma unroll
      for (int jd = 0; jd < 4; ++jd) {
        int g = ((jd * 2 + (l16 >> 3)) ^ srow) & 7;
        ob[rowoff + (g << 3) + (l16 & 7)] = f2bf(oacc[i][jd][r] * inv);
      }
    }
  }
}

// ---------------- launch ----------------

extern "C" void kernel_launch(void* const* d_in, const int* in_sizes, int n_in,
                              void* d_out, int out_size, void* d_ws, size_t ws_size,
                              hipStream_t stream) {
  const float* x    = (const float*)d_in[0];
  const float* wqkv = (const float*)d_in[1];
  const float* wout = (const float*)d_in[2];
  float* out = (float*)d_out;

  u16* ws    = (u16*)d_ws;
  u16* xb    = ws;                                   // 8192*1024  (reused as obuf)
  u16* wqkvb = xb + (size_t)8192 * 1024;             // 3072*1024
  u16* woutb = wqkvb + (size_t)3072 * 1024;          // 1024*1024
  u16* qbuf  = woutb + (size_t)1024 * 1024;          // [2,16,4096,64]
  u16* kbuf  = qbuf + (size_t)8388608;
  u16* vbuf  = kbuf + (size_t)8388608;
  u16* vtb   = vbuf + (size_t)8388608;               // operand-order V
  u16* obuf  = xb;                                   // alias: xb dead after gemm1

  cast_all_kernel<<<12288, 256, 0, stream>>>(x, wqkv, wout, ws);

  gemm_bt2<1><<<dim3(24, 32), 512, 0, stream>>>(xb, wqkvb, nullptr, qbuf, kbuf, vbuf,
                                                8192, 3072, 1024);
  pack_v<<<2048, 256, 0, stream>>>(vbuf, vtb);
  attn_kernel<<<1024, 256, 0, stream>>>(qbuf, kbuf, vtb, obuf);
  gemm_bt2<0><<<dim3(8, 32), 512, 0, stream>>>(obuf, woutb, out, nullptr, nullptr, nullptr,
                                               8192, 1024, 1024);
}

// Round 2
// 245.259 us; speedup vs baseline: 1.0571x; 1.0571x over previous
//
#include <hip/hip_runtime.h>
#include <hip/hip_bf16.h>

#define AS1 __attribute__((address_space(1)))
#define AS3 __attribute__((address_space(3)))

typedef unsigned short u16;
typedef short bf16x8 __attribute__((ext_vector_type(8)));
typedef unsigned short u16x8 __attribute__((ext_vector_type(8)));
typedef float f32x4 __attribute__((ext_vector_type(4)));

#define MFMA16 __builtin_amdgcn_mfma_f32_16x16x32_bf16

#define SBAR()  asm volatile("s_barrier" ::: "memory")
#define WAITV(N) asm volatile("s_waitcnt vmcnt(" #N ")" ::: "memory")
#define WAITL0() asm volatile("s_waitcnt lgkmcnt(0)" ::: "memory")

// ---------------- helpers ----------------

__device__ __forceinline__ u16 f2bf(float f) {        // RNE (finite data)
  union { float f; unsigned u; } c; c.f = f;
  unsigned u = c.u;
  u = u + 0x7fffu + ((u >> 16) & 1u);
  return (u16)(u >> 16);
}

__device__ __forceinline__ float fexp2(float x) {
#if __has_builtin(__builtin_amdgcn_exp2f)
  return __builtin_amdgcn_exp2f(x);
#else
  return exp2f(x);
#endif
}

// pack bf16(a) low16, bf16(b) high16 (truncating) — 1 v_perm_b32
__device__ __forceinline__ unsigned pack_bf(float a, float b) {
  union { float f; unsigned u; } ua, ub; ua.f = a; ub.f = b;
  return __builtin_amdgcn_perm(ub.u, ua.u, 0x07060302u);
}

__device__ __forceinline__ void gl_lds16(const void* g, void* l) {
  __builtin_amdgcn_global_load_lds((const AS1 void*)g, (AS3 void*)l, 16, 0, 0);
}

// ---------------- cast fp32 -> bf16, with 64-col-tile granule swizzle ----------------

__global__ void cast_all_kernel(const float* __restrict__ x,
                                const float* __restrict__ wqkv,
                                const float* __restrict__ wout,
                                u16* __restrict__ ws) {
  int i = blockIdx.x * blockDim.x + threadIdx.x;   // float4 index, 3145728 total
  const float4* src;
  int rel;
  size_t matbase;
  if (i < 2097152)      { src = (const float4*)x + i;                rel = i;           matbase = 0; }
  else if (i < 2883584) { src = (const float4*)wqkv + (i - 2097152); rel = i - 2097152; matbase = 8388608; }
  else                  { src = (const float4*)wout + (i - 2883584); rel = i - 2883584; matbase = 11534336; }
  float4 f = *src;
  ushort4 o;
  o.x = f2bf(f.x); o.y = f2bf(f.y); o.z = f2bf(f.z); o.w = f2bf(f.w);
  int fe  = rel * 4;
  int row = fe >> 10, c = fe & 1023;
  int newc = (c & ~63) | (((((c >> 3) ^ row) & 7) << 3)) | (c & 7);
  ((ushort4*)ws)[(matbase + (size_t)row * 1024 + newc) >> 2] = o;
}

// ---------------- gemm_qkv: 256x256 tile, 8 waves (2Mx4N), 4 quadrant-phases/K-tile ----
// m201-geometry: per phase {<=12 ds_reads; stage 1 unit (2 gl_lds); s_barrier; lgkmcnt(0);
// setprio(1); 16 MFMA; setprio(0); s_barrier}. Units per K-tile: Ae(A rows {0-63,128-191}),
// Ao({64-127,192-255}), Be(B nh0 32-row blocks), Bo(B nh1). Stage slots: ph0->Ao(X+1),
// ph1->Ae(X+2), ph2->Be(X+2), ph3->Bo(X+2). Reads: ph0: A0+B0 (12), ph1: B1 (4),
// ph2: A1 (8), ph3: none. Single gate vmcnt(6) at ph3 (3 units stay in flight; tile X+1
// fully landed). vmcnt(0) only for the last two tiles. No __syncthreads anywhere.

__global__ __launch_bounds__(512, 2) void gemm_qkv(
    const u16* __restrict__ A, const u16* __restrict__ Bm,
    u16* __restrict__ qd, u16* __restrict__ kd, u16* __restrict__ vd,
    int M, int N, int K)
{
  __shared__ u16 As[2][256 * 64];   // 64 KB
  __shared__ u16 Bs[2][256 * 64];   // 64 KB

  const int tid  = threadIdx.x;
  const int wave = tid >> 6, lane = tid & 63;
  const int quad = lane >> 4, l16 = lane & 15;
  const int wr = wave >> 2, wc = wave & 3;   // wave grid 2M x 4N

  // bijective XCD-aware swizzle (384 blocks, 384 % 8 == 0)
  const int gx  = gridDim.x;                  // N panels
  const int nwg = gx * gridDim.y;
  const int lin = blockIdx.y * gx + blockIdx.x;
  const int q8  = nwg >> 3;
  const int swz = (lin & 7) * q8 + (lin >> 3);
  const int bm = (swz / gx) * 256;
  const int bn = (swz % gx) * 256;

  // per-lane staging source addresses (8-row wave slice, 64-col K-chunk)
  const int sr = lane >> 3;          // 0..7
  const int sc = (lane & 7) * 8;
  const u16* Abase = A  + (size_t)(bm + wave * 8 + sr) * K + sc;
  const u16* Bbase = Bm + (size_t)(bn + sr) * K + sc;
  const int w4 = (wave >> 2) * 64 + (wave & 3) * 8;   // B staging row pattern

  const int NT = K >> 6;

  auto stA = [&](int t, int h) {     // h=0: even 64-row blocks, h=1: odd
    const int d = t & 1;
    #pragma unroll
    for (int c = 0; c < 2; ++c) {
      int rb = h * 64 + c * 128;
      gl_lds16(Abase + (size_t)rb * K + (size_t)t * 64,
               &As[d][(rb + wave * 8) * 64]);
    }
  };
  auto stB = [&](int t, int h) {     // h=0: nh0 32-row blocks, h=1: nh1
    const int d = t & 1;
    #pragma unroll
    for (int c = 0; c < 2; ++c) {
      int rb = w4 + h * 32 + c * 128;
      gl_lds16(Bbase + (size_t)rb * K + (size_t)t * 64,
               &Bs[d][rb * 64]);
    }
  };
  auto rdA = [&](int d, int mf, int g) -> bf16x8 {
    int row = wr * 128 + mf * 16 + l16;
    return *(const bf16x8*)&As[d][row * 64 + (((g ^ row) & 7) << 3)];
  };
  auto rdB = [&](int d, int nf, int g) -> bf16x8 {
    int row = wc * 64 + nf * 16 + l16;
    return *(const bf16x8*)&Bs[d][row * 64 + (((g ^ row) & 7) << 3)];
  };

  f32x4 acc[8][4] = {};
  bf16x8 aA[4][2];   // current A quadrant frags [mf][kk]
  bf16x8 bB[4][2];   // B frags, both nh halves alive [nf][kk]

  // ---- prologue: units in stream order Ae0 Be0 Bo0 Ao0 Ae1 Be1 Bo1; gate tile0 ----
  stA(0, 0); stB(0, 0); stB(0, 1); stA(0, 1);
  stA(1, 0); stB(1, 0); stB(1, 1);
  WAITV(6);                      // all but newest 3 units -> tile 0 fully landed
  SBAR();

  for (int X = 0; X < NT; ++X) {
    const int d  = X & 1;
    const bool s1 = (X + 1 < NT);
    const bool s2 = (X + 2 < NT);

    // ===== ph0: quadrant (mh0, nh0); reads A0 (8) + B0 (4); stage Ao(X+1) =====
    #pragma unroll
    for (int mf = 0; mf < 4; ++mf) { aA[mf][0] = rdA(d, mf, quad); aA[mf][1] = rdA(d, mf, quad + 4); }
    #pragma unroll
    for (int nf = 0; nf < 2; ++nf) { bB[nf][0] = rdB(d, nf, quad); bB[nf][1] = rdB(d, nf, quad + 4); }
    if (s1) stA(X + 1, 1);
    SBAR();
    WAITL0();
    __builtin_amdgcn_s_setprio(1);
    #pragma unroll
    for (int mf = 0; mf < 4; ++mf)
      #pragma unroll
      for (int nf = 0; nf < 2; ++nf) {
        acc[mf][nf] = MFMA16(aA[mf][0], bB[nf][0], acc[mf][nf], 0, 0, 0);
        acc[mf][nf] = MFMA16(aA[mf][1], bB[nf][1], acc[mf][nf], 0, 0, 0);
      }
    __builtin_amdgcn_s_setprio(0);
    SBAR();

    // ===== ph1: quadrant (mh0, nh1); reads B1 (4); stage Ae(X+2) =====
    #pragma unroll
    for (int nf = 2; nf < 4; ++nf) { bB[nf][0] = rdB(d, nf, quad); bB[nf][1] = rdB(d, nf, quad + 4); }
    if (s2) stA(X + 2, 0);
    SBAR();
    WAITL0();
    __builtin_amdgcn_s_setprio(1);
    #pragma unroll
    for (int mf = 0; mf < 4; ++mf)
      #pragma unroll
      for (int nf = 2; nf < 4; ++nf) {
        acc[mf][nf] = MFMA16(aA[mf][0], bB[nf][0], acc[mf][nf], 0, 0, 0);
        acc[mf][nf] = MFMA16(aA[mf][1], bB[nf][1], acc[mf][nf], 0, 0, 0);
      }
    __builtin_amdgcn_s_setprio(0);
    SBAR();

    // ===== ph2: quadrant (mh1, nh0); reads A1 (8, overwrite aA); stage Be(X+2) =====
    #pragma unroll
    for (int mf = 0; mf < 4; ++mf) { aA[mf][0] = rdA(d, mf + 4, quad); aA[mf][1] = rdA(d, mf + 4, quad + 4); }
    if (s2) stB(X + 2, 0);
    SBAR();
    WAITL0();
    __builtin_amdgcn_s_setprio(1);
    #pragma unroll
    for (int mf = 0; mf < 4; ++mf)
      #pragma unroll
      for (int nf = 0; nf < 2; ++nf) {
        acc[mf + 4][nf] = MFMA16(aA[mf][0], bB[nf][0], acc[mf + 4][nf], 0, 0, 0);
        acc[mf + 4][nf] = MFMA16(aA[mf][1], bB[nf][1], acc[mf + 4][nf], 0, 0, 0);
      }
    __builtin_amdgcn_s_setprio(0);
    SBAR();

    // ===== ph3: quadrant (mh1, nh1); no reads; stage Bo(X+2); gate vmcnt =====
    if (s2) stB(X + 2, 1);
    SBAR();
    __builtin_amdgcn_s_setprio(1);
    #pragma unroll
    for (int mf = 0; mf < 4; ++mf)
      #pragma unroll
      for (int nf = 2; nf < 4; ++nf) {
        acc[mf + 4][nf] = MFMA16(aA[mf][0], bB[nf][0], acc[mf + 4][nf], 0, 0, 0);
        acc[mf + 4][nf] = MFMA16(aA[mf][1], bB[nf][1], acc[mf + 4][nf], 0, 0, 0);
      }
    __builtin_amdgcn_s_setprio(0);
    if (s1) {
      if (s2) { WAITV(6); }      // tile X+1 fully landed; 3 units stay in flight
      else    { WAITV(0); }      // tail drain (once)
    }
    SBAR();
  }

  // ---- epilogue: QKV remap (same as proven 128-tile version) ----
  #pragma unroll
  for (int mf = 0; mf < 8; ++mf) {
    #pragma unroll
    for (int nf = 0; nf < 4; ++nf) {
      #pragma unroll
      for (int r = 0; r < 4; ++r) {
        int m = bm + wr * 128 + mf * 16 + quad * 4 + r;
        int n = bn + wc * 64 + nf * 16 + l16;
        float val = acc[mf][nf][r];
        int part = n >> 10, rem = n & 1023;
        int h = rem >> 6, dcol = rem & 63;
        int b = m >> 12, s = m & 4095;
        if (part == 0) val *= 0.1803368801111244f;   // 0.125 * log2(e), exp2 path
        u16* dst = (part == 0) ? qd : (part == 1) ? kd : vd;
        dst[((size_t)((b * 16 + h) * 4096 + s)) * 64 + dcol] = f2bf(val);
      }
    }
  }
}

// ---------------- GEMM (proven round-0): C[M,N] = A[M,K] * B[N,K]^T ----------------

template<int EPI>
__global__ __launch_bounds__(256) void gemm_bt(
    const u16* __restrict__ A, const u16* __restrict__ Bm,
    float* __restrict__ Cf,
    u16* __restrict__ qd, u16* __restrict__ kd, u16* __restrict__ vd,
    int M, int N, int K)
{
  __shared__ u16 As[128 * 64];
  __shared__ u16 Bs[128 * 64];

  const int tid  = threadIdx.x;
  const int wave = tid >> 6, lane = tid & 63;
  const int quad = lane >> 4, l16 = lane & 15;
  const int bm = blockIdx.y * 128, bn = blockIdx.x * 128;
  const int wm = (wave >> 1) * 64, wn = (wave & 1) * 64;

  f32x4 acc[4][4] = {};

  const int srow = wave * 32 + (lane >> 3);
  const int scol = (lane & 7) * 8;

  for (int kt = 0; kt < K; kt += 64) {
    __syncthreads();
    #pragma unroll
    for (int i = 0; i < 4; ++i) {
      gl_lds16(&A[(size_t)(bm + srow + i * 8) * K + kt + scol], &As[(wave * 32 + i * 8) * 64]);
      gl_lds16(&Bm[(size_t)(bn + srow + i * 8) * K + kt + scol], &Bs[(wave * 32 + i * 8) * 64]);
    }
    __syncthreads();
    #pragma unroll
    for (int kk = 0; kk < 64; kk += 32) {
      bf16x8 af[4], bb[4];
      #pragma unroll
      for (int i = 0; i < 4; ++i) {
        int row = wm + i * 16 + l16;
        af[i] = *(const bf16x8*)&As[row * 64 + (((((kk >> 3) + quad) ^ row) & 7) << 3)];
      }
      #pragma unroll
      for (int j = 0; j < 4; ++j) {
        int row = wn + j * 16 + l16;
        bb[j] = *(const bf16x8*)&Bs[row * 64 + (((((kk >> 3) + quad) ^ row) & 7) << 3)];
      }
      #pragma unroll
      for (int i = 0; i < 4; ++i)
        #pragma unroll
        for (int j = 0; j < 4; ++j)
          acc[i][j] = MFMA16(af[i], bb[j], acc[i][j], 0, 0, 0);
    }
  }

  #pragma unroll
  for (int i = 0; i < 4; ++i) {
    #pragma unroll
    for (int j = 0; j < 4; ++j) {
      #pragma unroll
      for (int r = 0; r < 4; ++r) {
        int m = bm + wm + i * 16 + quad * 4 + r;
        int n = bn + wn + j * 16 + l16;
        float val = acc[i][j][r];
        if (EPI == 0) {
          Cf[(size_t)m * N + n] = val;
        } else {
          int part = n >> 10, rem = n & 1023;
          int h = rem >> 6, d = rem & 63;
          int b = m >> 12, s = m & 4095;
          if (part == 0) val *= 0.1803368801111244f;
          u16* dst = (part == 0) ? qd : (part == 1) ? kd : vd;
          dst[((size_t)((b * 16 + h) * 4096 + s)) * 64 + d] = f2bf(val);
        }
      }
    }
  }
}

// ---------------- V pack: [B,H,S,64] -> operand-order [B,H, tile(64), jd(4), h(2), lane(64), 8] ----

__global__ __launch_bounds__(256) void pack_v(const u16* __restrict__ vb,
                                              u16* __restrict__ vt) {
  __shared__ u16 Lt[64 * 72];
  const int tid = threadIdx.x, bid = blockIdx.x;
  const int bh = bid & 31, t = bid >> 5;
  const size_t base = (size_t)bh << 18;
  #pragma unroll
  for (int c = 0; c < 2; ++c) {
    int idx = tid * 8 + c * 2048;
    int row = idx >> 6, col = idx & 63;                 // row=key, col=dh
    u16x8 vv = *(const u16x8*)&vb[base + (size_t)(t * 64 + row) * 64 + col];
    #pragma unroll
    for (int s = 0; s < 8; ++s) Lt[(col + s) * 72 + row] = vv[s];
  }
  __syncthreads();
  #pragma unroll
  for (int c = 0; c < 2; ++c) {
    int w = tid + c * 256;                              // 512 chunks
    int dh = w >> 3, k8 = w & 7;
    u16x8 o;
    #pragma unroll
    for (int s = 0; s < 8; ++s) o[s] = Lt[dh * 72 + k8 * 8 + s];
    int off = ((dh >> 4) << 10) | ((k8 >> 2) << 9) | ((k8 & 3) << 7) | ((dh & 15) << 3);
    *(u16x8*)&vt[base + (size_t)t * 4096 + off] = o;
  }
}

// ---------------- attention: 4 independent waves/block, S^T trick, coalesced V ----------------

__global__ __launch_bounds__(256) void attn_kernel(
    const u16* __restrict__ qb, const u16* __restrict__ kb,
    const u16* __restrict__ vt, u16* __restrict__ ob)
{
  __shared__ u16 Ps[4][32 * 64];

  const int tid  = threadIdx.x;
  const int wave = tid >> 6;
  const int lane = tid & 63;
  const int quad = lane >> 4, l16 = lane & 15;
  const int bid  = blockIdx.x;
  const int bh   = bid & 31;
  const int t0   = (((bid >> 5) << 2) | wave) << 5;
  const size_t base = (size_t)bh << 18;
  u16* __restrict__ ps = &Ps[wave][0];

  const int l64 = l16 * 64 + quad * 8;
  const u16* vbase = vt + base + lane * 8;   // + tile*4096 + jd*1024 + h*512

  // Q B-fragments (B[n=query l16][k=dh]); q pre-scaled by 0.125*log2e
  const u16* qp = qb + base + (size_t)t0 * 64 + l64;
  bf16x8 bq00 = *(const bf16x8*)(qp);
  bf16x8 bq01 = *(const bf16x8*)(qp + 32);
  bf16x8 bq10 = *(const bf16x8*)(qp + 1024);
  bf16x8 bq11 = *(const bf16x8*)(qp + 1056);

  f32x4 oacc[2][4] = {};
  f32x4 lacc[2] = {};
  bf16x8 ones;
  #pragma unroll
  for (int s = 0; s < 8; ++s) ones[s] = (short)0x3F80;

  const int lo = max(0, t0 - 511) >> 6;
  const int hi = (t0 + 31) >> 6;

  auto loadK = [&](int kb0, bf16x8 (&kf)[4][2]) {
    #pragma unroll
    for (int j = 0; j < 4; ++j) {
      const u16* krow = kb + base + (size_t)(kb0 + j * 16) * 64 + l64;
      kf[j][0] = *(const bf16x8*)(krow);
      kf[j][1] = *(const bf16x8*)(krow + 32);
    }
  };

  bf16x8 ka[4][2], kb2[4][2];

  // ======== prefix tile (keys 0..15 causal; keys 16..31 zero-filled) ========
  {
    const u16* kpre = kb + base + l64;
    bf16x8 pk0 = *(const bf16x8*)(kpre);
    bf16x8 pk1 = *(const bf16x8*)(kpre + 32);
    loadK(lo << 6, ka);                        // prefetch first window tile
    bf16x8 pv[4];
    #pragma unroll
    for (int jd = 0; jd < 4; ++jd)
      pv[jd] = *(const bf16x8*)(vbase + jd * 1024);   // tile 0, h=0

    #pragma unroll
    for (int i = 0; i < 2; ++i) {
      f32x4 t4 = {};
      t4 = MFMA16(pk0, i ? bq10 : bq00, t4, 0, 0, 0);
      t4 = MFMA16(pk1, i ? bq11 : bq01, t4, 0, 0, 0);
      int row = i * 16 + l16;
      int qpos = t0 + row;
      float p[4];
      #pragma unroll
      for (int r = 0; r < 4; ++r) {
        int kpos = quad * 4 + r;
        p[r] = (kpos <= qpos) ? fexp2(t4[r]) : 0.f;
      }
      uint2 w;
      w.x = pack_bf(p[0], p[1]);
      w.y = pack_bf(p[2], p[3]);
      *(uint2*)&ps[row * 64 + ((quad ^ l16) & 15) * 4] = w;
      uint2 z; z.x = 0u; z.y = 0u;
      *(uint2*)&ps[row * 64 + (((4 + quad) ^ l16) & 15) * 4] = z;
    }
    #pragma unroll
    for (int i = 0; i < 2; ++i) {
      int row = i * 16 + l16;
      uint2 r0 = *(uint2*)&ps[row * 64 + (((2 * quad) ^ l16) & 15) * 4];
      uint2 r1 = *(uint2*)&ps[row * 64 + (((2 * quad + 1) ^ l16) & 15) * 4];
      union { uint4 u; bf16x8 v; } cc; cc.u = make_uint4(r0.x, r0.y, r1.x, r1.y);
      bf16x8 ap = cc.v;
      lacc[i] = MFMA16(ap, ones, lacc[i], 0, 0, 0);
      #pragma unroll
      for (int jd = 0; jd < 4; ++jd)
        oacc[i][jd] = MFMA16(ap, pv[jd], oacc[i][jd], 0, 0, 0);
    }
  }

  // ======== sliding-window tiles ========
  auto tilec = [&](int kb0, bf16x8 (&kf)[4][2]) {
    #pragma unroll
    for (int j = 0; j < 4; ++j) {
      const int kmin = kb0 + j * 16;
      #pragma unroll
      for (int i = 0; i < 2; ++i) {
        const int qmin = t0 + i * 16;
        const int row  = i * 16 + l16;
        uint2* dst = (uint2*)&ps[row * 64 + (((j * 4 + quad) ^ l16) & 15) * 4];
        // wave-uniform subtile classification
        const bool sub_masked = (kmin > qmin + 15) || (qmin - kmin >= 527) || (kmin < 16);
        if (sub_masked) { uint2 z; z.x = 0u; z.y = 0u; *dst = z; continue; }
        f32x4 t4 = {};
        t4 = MFMA16(kf[j][0], i ? bq10 : bq00, t4, 0, 0, 0);
        t4 = MFMA16(kf[j][1], i ? bq11 : bq01, t4, 0, 0, 0);
        const bool sub_ok = (kmin + 15 <= qmin) && (qmin + 15 - kmin < 512);
        float p[4];
        if (sub_ok) {
          #pragma unroll
          for (int r = 0; r < 4; ++r) p[r] = fexp2(t4[r]);
        } else {
          int qpos = t0 + row;
          #pragma unroll
          for (int r = 0; r < 4; ++r) {
            int kpos = kmin + quad * 4 + r;       // kmin >= 16 guaranteed here
            unsigned diff = (unsigned)(qpos - kpos);
            p[r] = (diff < 512u) ? fexp2(t4[r]) : 0.f;
          }
        }
        uint2 w;
        w.x = pack_bf(p[0], p[1]);
        w.y = pack_bf(p[2], p[3]);
        *dst = w;
      }
    }
    // PV + l accumulation; V frags contiguous 1KB each, reused across i
    const u16* vp = vbase + (size_t)kb0 * 64;
    #pragma unroll
    for (int h = 0; h < 2; ++h) {
      bf16x8 bv0 = *(const bf16x8*)(vp + h * 512);
      bf16x8 bv1 = *(const bf16x8*)(vp + 1024 + h * 512);
      bf16x8 bv2 = *(const bf16x8*)(vp + 2048 + h * 512);
      bf16x8 bv3 = *(const bf16x8*)(vp + 3072 + h * 512);
      #pragma unroll
      for (int i = 0; i < 2; ++i) {
        int row = i * 16 + l16;
        int g0 = h * 8 + 2 * quad;
        uint2 r0 = *(uint2*)&ps[row * 64 + ((g0 ^ l16) & 15) * 4];
        uint2 r1 = *(uint2*)&ps[row * 64 + (((g0 + 1) ^ l16) & 15) * 4];
        union { uint4 u; bf16x8 v; } cc; cc.u = make_uint4(r0.x, r0.y, r1.x, r1.y);
        bf16x8 ap = cc.v;
        lacc[i] = MFMA16(ap, ones, lacc[i], 0, 0, 0);
        oacc[i][0] = MFMA16(ap, bv0, oacc[i][0], 0, 0, 0);
        oacc[i][1] = MFMA16(ap, bv1, oacc[i][1], 0, 0, 0);
        oacc[i][2] = MFMA16(ap, bv2, oacc[i][2], 0, 0, 0);
        oacc[i][3] = MFMA16(ap, bv3, oacc[i][3], 0, 0, 0);
      }
    }
  };

  for (int t = lo; t <= hi; t += 2) {
    if (t + 1 <= hi) loadK((t + 1) << 6, kb2);
    tilec(t << 6, ka);
    if (t + 1 <= hi) {
      if (t + 2 <= hi) loadK((t + 2) << 6, ka);
      tilec((t + 1) << 6, kb2);
    }
  }

  // ---- epilogue: O/l -> bf16 [B,S,H*64], granule-swizzled for GEMM3 staging ----
  const int b = bh >> 4, h = bh & 15;
  #pragma unroll
  for (int i = 0; i < 2; ++i) {
    #pragma unroll
    for (int r = 0; r < 4; ++r) {
      float inv = 1.f / lacc[i][r];
      int srow = t0 + i * 16 + quad * 4 + r;
      size_t rowoff = ((size_t)(b * 4096 + srow)) * 1024 + h * 64;
      #pragma unroll
      for (int jd = 0; jd < 4; ++jd) {
        int g = ((jd * 2 + (l16 >> 3)) ^ srow) & 7;
        ob[rowoff + (g << 3) + (l16 & 7)] = f2bf(oacc[i][jd][r] * inv);
      }
    }
  }
}

// ---------------- launch ----------------

extern "C" void kernel_launch(void* const* d_in, const int* in_sizes, int n_in,
                              void* d_out, int out_size, void* d_ws, size_t ws_size,
                              hipStream_t stream) {
  const float* x    = (const float*)d_in[0];
  const float* wqkv = (const float*)d_in[1];
  const float* wout = (const float*)d_in[2];
  float* out = (float*)d_out;

  u16* ws    = (u16*)d_ws;
  u16* xb    = ws;                                   // 8192*1024  (reused as obuf)
  u16* wqkvb = xb + (size_t)8192 * 1024;             // 3072*1024
  u16* woutb = wqkvb + (size_t)3072 * 1024;          // 1024*1024
  u16* qbuf  = woutb + (size_t)1024 * 1024;          // [2,16,4096,64]
  u16* kbuf  = qbuf + (size_t)8388608;
  u16* vbuf  = kbuf + (size_t)8388608;
  u16* vtb   = vbuf + (size_t)8388608;               // operand-order V
  u16* obuf  = xb;                                   // alias: xb dead after gemm1

  cast_all_kernel<<<12288, 256, 0, stream>>>(x, wqkv, wout, ws);

  gemm_qkv<<<dim3(12, 32), 512, 0, stream>>>(xb, wqkvb, qbuf, kbuf, vbuf,
                                             8192, 3072, 1024);
  pack_v<<<2048, 256, 0, stream>>>(vbuf, vtb);
  attn_kernel<<<1024, 256, 0, stream>>>(qbuf, kbuf, vtb, obuf);
  gemm_bt<0><<<dim3(8, 64), 256, 0, stream>>>(obuf, woutb, out, nullptr, nullptr, nullptr,
                                              8192, 1024, 1024);
}

// Round 3
// 233.175 us; speedup vs baseline: 1.1119x; 1.0518x over previous
//
#include <hip/hip_runtime.h>
#include <hip/hip_bf16.h>

#define AS1 __attribute__((address_space(1)))
#define AS3 __attribute__((address_space(3)))

typedef unsigned short u16;
typedef short bf16x8 __attribute__((ext_vector_type(8)));
typedef unsigned short u16x8 __attribute__((ext_vector_type(8)));
typedef float f32x4 __attribute__((ext_vector_type(4)));

#define MFMA16 __builtin_amdgcn_mfma_f32_16x16x32_bf16

// ---------------- helpers ----------------

__device__ __forceinline__ u16 f2bf(float f) {        // RNE (finite data)
  union { float f; unsigned u; } c; c.f = f;
  unsigned u = c.u;
  u = u + 0x7fffu + ((u >> 16) & 1u);
  return (u16)(u >> 16);
}

__device__ __forceinline__ float fexp2(float x) {
#if __has_builtin(__builtin_amdgcn_exp2f)
  return __builtin_amdgcn_exp2f(x);
#else
  return exp2f(x);
#endif
}

// pack bf16(a) low16, bf16(b) high16 (truncating) — 1 v_perm_b32
__device__ __forceinline__ unsigned pack_bf(float a, float b) {
  union { float f; unsigned u; } ua, ub; ua.f = a; ub.f = b;
  return __builtin_amdgcn_perm(ub.u, ua.u, 0x07060302u);
}

__device__ __forceinline__ void gl_lds16(const void* g, void* l) {
  __builtin_amdgcn_global_load_lds((const AS1 void*)g, (AS3 void*)l, 16, 0, 0);
}

// ---------------- cast fp32 -> bf16, with 64-col-tile granule swizzle ----------------

__global__ void cast_all_kernel(const float* __restrict__ x,
                                const float* __restrict__ wqkv,
                                const float* __restrict__ wout,
                                u16* __restrict__ ws) {
  int i = blockIdx.x * blockDim.x + threadIdx.x;   // float4 index, 3145728 total
  const float4* src;
  int rel;
  size_t matbase;
  if (i < 2097152)      { src = (const float4*)x + i;                rel = i;           matbase = 0; }
  else if (i < 2883584) { src = (const float4*)wqkv + (i - 2097152); rel = i - 2097152; matbase = 8388608; }
  else                  { src = (const float4*)wout + (i - 2883584); rel = i - 2883584; matbase = 11534336; }
  float4 f = *src;
  ushort4 o;
  o.x = f2bf(f.x); o.y = f2bf(f.y); o.z = f2bf(f.z); o.w = f2bf(f.w);
  int fe  = rel * 4;
  int row = fe >> 10, c = fe & 1023;
  int newc = (c & ~63) | (((((c >> 3) ^ row) & 7) << 3)) | (c & 7);
  ((ushort4*)ws)[(matbase + (size_t)row * 1024 + newc) >> 2] = o;
}

// ---------------- GEMM: C[M,N] = A[M,K] * B[N,K]^T  (bf16 in, fp32 acc) ----------------
// Round-0 proven main loop. EPI==1: QKV epilogue; V-part blocks (bn>=2048) write V directly
// in attn operand order (pack_v fused away): value (key=s&63, dh) at
//   vt[(b*16+h)<<18 | t*4096 | jd*1024 | h2*512 | (q2*16+l16)*8 | ss]
// with t=s>>6, k6=s&63, h2=k6>>5, q2=(k6>>3)&3, ss=k6&7, jd=(dh>>4) — r=0..3 are
// contiguous u16 -> one 8B store per (i,j).

template<int EPI>
__global__ __launch_bounds__(256) void gemm_bt(
    const u16* __restrict__ A, const u16* __restrict__ Bm,
    float* __restrict__ Cf,
    u16* __restrict__ qd, u16* __restrict__ kd, u16* __restrict__ vd,
    int M, int N, int K)
{
  __shared__ u16 As[128 * 64];
  __shared__ u16 Bs[128 * 64];

  const int tid  = threadIdx.x;
  const int wave = tid >> 6, lane = tid & 63;
  const int quad = lane >> 4, l16 = lane & 15;
  const int bm = blockIdx.y * 128, bn = blockIdx.x * 128;
  const int wm = (wave >> 1) * 64, wn = (wave & 1) * 64;

  f32x4 acc[4][4] = {};

  const int srow = wave * 32 + (lane >> 3);
  const int scol = (lane & 7) * 8;

  for (int kt = 0; kt < K; kt += 64) {
    __syncthreads();
    #pragma unroll
    for (int i = 0; i < 4; ++i) {
      gl_lds16(&A[(size_t)(bm + srow + i * 8) * K + kt + scol], &As[(wave * 32 + i * 8) * 64]);
      gl_lds16(&Bm[(size_t)(bn + srow + i * 8) * K + kt + scol], &Bs[(wave * 32 + i * 8) * 64]);
    }
    __syncthreads();
    #pragma unroll
    for (int kk = 0; kk < 64; kk += 32) {
      bf16x8 af[4], bb[4];
      #pragma unroll
      for (int i = 0; i < 4; ++i) {
        int row = wm + i * 16 + l16;
        af[i] = *(const bf16x8*)&As[row * 64 + (((((kk >> 3) + quad) ^ row) & 7) << 3)];
      }
      #pragma unroll
      for (int j = 0; j < 4; ++j) {
        int row = wn + j * 16 + l16;
        bb[j] = *(const bf16x8*)&Bs[row * 64 + (((((kk >> 3) + quad) ^ row) & 7) << 3)];
      }
      #pragma unroll
      for (int i = 0; i < 4; ++i)
        #pragma unroll
        for (int j = 0; j < 4; ++j)
          acc[i][j] = MFMA16(af[i], bb[j], acc[i][j], 0, 0, 0);
    }
  }

  const int partU = bn >> 10;          // block-uniform (128 | 1024)
  if (EPI == 1 && partU == 2) {
    // ---- fused pack_v: write V straight into operand-order vt ----
    const int b = bm >> 12;
    #pragma unroll
    for (int i = 0; i < 4; ++i) {
      int s0q = (bm + wm + i * 16 + quad * 4) & 4095;
      int t  = s0q >> 6, k6 = s0q & 63;
      int h2 = k6 >> 5, q2 = (k6 >> 3) & 3, ssb = k6 & 7;
      #pragma unroll
      for (int j = 0; j < 4; ++j) {
        int nbase = bn + wn + j * 16;
        int h  = (nbase >> 6) & 15;
        int jd = (nbase & 63) >> 4;
        unsigned lo = (unsigned)f2bf(acc[i][j][0]) | ((unsigned)f2bf(acc[i][j][1]) << 16);
        unsigned hi = (unsigned)f2bf(acc[i][j][2]) | ((unsigned)f2bf(acc[i][j][3]) << 16);
        uint2 w; w.x = lo; w.y = hi;
        *(uint2*)&vd[(((size_t)(b * 16 + h)) << 18) + (size_t)t * 4096
                     + jd * 1024 + h2 * 512 + (q2 * 16 + l16) * 8 + ssb] = w;
      }
    }
  } else {
    #pragma unroll
    for (int i = 0; i < 4; ++i) {
      #pragma unroll
      for (int j = 0; j < 4; ++j) {
        #pragma unroll
        for (int r = 0; r < 4; ++r) {
          int m = bm + wm + i * 16 + quad * 4 + r;
          int n = bn + wn + j * 16 + l16;
          float val = acc[i][j][r];
          if (EPI == 0) {
            Cf[(size_t)m * N + n] = val;
          } else {
            int part = n >> 10, rem = n & 1023;
            int h = rem >> 6, d = rem & 63;
            int b = m >> 12, s = m & 4095;
            if (part == 0) val *= 0.1803368801111244f;   // 0.125 * log2(e), exp2 path
            u16* dst = (part == 0) ? qd : kd;            // part 2 handled above
            dst[((size_t)((b * 16 + h) * 4096 + s)) * 64 + d] = f2bf(val);
          }
        }
      }
    }
  }
}

// ---------------- attention: 4 independent waves/block, S^T trick, coalesced V ----------------

__global__ __launch_bounds__(256) void attn_kernel(
    const u16* __restrict__ qb, const u16* __restrict__ kb,
    const u16* __restrict__ vt, u16* __restrict__ ob)
{
  __shared__ u16 Ps[4][32 * 64];

  const int tid  = threadIdx.x;
  const int wave = tid >> 6;
  const int lane = tid & 63;
  const int quad = lane >> 4, l16 = lane & 15;
  const int bid  = blockIdx.x;
  const int bh   = bid & 31;
  const int t0   = (((bid >> 5) << 2) | wave) << 5;
  const size_t base = (size_t)bh << 18;
  u16* __restrict__ ps = &Ps[wave][0];

  const int l64 = l16 * 64 + quad * 8;
  const u16* vbase = vt + base + lane * 8;   // + tile*4096 + jd*1024 + h*512

  // Q B-fragments (B[n=query l16][k=dh]); q pre-scaled by 0.125*log2e
  const u16* qp = qb + base + (size_t)t0 * 64 + l64;
  bf16x8 bq00 = *(const bf16x8*)(qp);
  bf16x8 bq01 = *(const bf16x8*)(qp + 32);
  bf16x8 bq10 = *(const bf16x8*)(qp + 1024);
  bf16x8 bq11 = *(const bf16x8*)(qp + 1056);

  f32x4 oacc[2][4] = {};
  f32x4 lacc[2] = {};
  bf16x8 ones;
  #pragma unroll
  for (int s = 0; s < 8; ++s) ones[s] = (short)0x3F80;

  const int lo = max(0, t0 - 511) >> 6;
  const int hi = (t0 + 31) >> 6;

  auto loadK = [&](int kb0, bf16x8 (&kf)[4][2]) {
    #pragma unroll
    for (int j = 0; j < 4; ++j) {
      const u16* krow = kb + base + (size_t)(kb0 + j * 16) * 64 + l64;
      kf[j][0] = *(const bf16x8*)(krow);
      kf[j][1] = *(const bf16x8*)(krow + 32);
    }
  };

  bf16x8 ka[4][2], kb2[4][2];

  // ======== prefix tile (keys 0..15 causal; keys 16..31 zero-filled) ========
  {
    const u16* kpre = kb + base + l64;
    bf16x8 pk0 = *(const bf16x8*)(kpre);
    bf16x8 pk1 = *(const bf16x8*)(kpre + 32);
    loadK(lo << 6, ka);                        // prefetch first window tile
    bf16x8 pv[4];
    #pragma unroll
    for (int jd = 0; jd < 4; ++jd)
      pv[jd] = *(const bf16x8*)(vbase + jd * 1024);   // tile 0, h=0

    #pragma unroll
    for (int i = 0; i < 2; ++i) {
      f32x4 t4 = {};
      t4 = MFMA16(pk0, i ? bq10 : bq00, t4, 0, 0, 0);
      t4 = MFMA16(pk1, i ? bq11 : bq01, t4, 0, 0, 0);
      int row = i * 16 + l16;
      int qpos = t0 + row;
      float p[4];
      #pragma unroll
      for (int r = 0; r < 4; ++r) {
        int kpos = quad * 4 + r;
        p[r] = (kpos <= qpos) ? fexp2(t4[r]) : 0.f;
      }
      uint2 w;
      w.x = pack_bf(p[0], p[1]);
      w.y = pack_bf(p[2], p[3]);
      *(uint2*)&ps[row * 64 + ((quad ^ l16) & 15) * 4] = w;
      uint2 z; z.x = 0u; z.y = 0u;
      *(uint2*)&ps[row * 64 + (((4 + quad) ^ l16) & 15) * 4] = z;
    }
    #pragma unroll
    for (int i = 0; i < 2; ++i) {
      int row = i * 16 + l16;
      uint2 r0 = *(uint2*)&ps[row * 64 + (((2 * quad) ^ l16) & 15) * 4];
      uint2 r1 = *(uint2*)&ps[row * 64 + (((2 * quad + 1) ^ l16) & 15) * 4];
      union { uint4 u; bf16x8 v; } cc; cc.u = make_uint4(r0.x, r0.y, r1.x, r1.y);
      bf16x8 ap = cc.v;
      __builtin_amdgcn_s_setprio(1);
      lacc[i] = MFMA16(ap, ones, lacc[i], 0, 0, 0);
      #pragma unroll
      for (int jd = 0; jd < 4; ++jd)
        oacc[i][jd] = MFMA16(ap, pv[jd], oacc[i][jd], 0, 0, 0);
      __builtin_amdgcn_s_setprio(0);
    }
  }

  // ======== sliding-window tiles ========
  auto tilec = [&](int kb0, bf16x8 (&kf)[4][2]) {
    #pragma unroll
    for (int j = 0; j < 4; ++j) {
      const int kmin = kb0 + j * 16;
      #pragma unroll
      for (int i = 0; i < 2; ++i) {
        const int qmin = t0 + i * 16;
        const int row  = i * 16 + l16;
        uint2* dst = (uint2*)&ps[row * 64 + (((j * 4 + quad) ^ l16) & 15) * 4];
        // wave-uniform subtile classification
        const bool sub_masked = (kmin > qmin + 15) || (qmin - kmin >= 527) || (kmin < 16);
        if (sub_masked) { uint2 z; z.x = 0u; z.y = 0u; *dst = z; continue; }
        f32x4 t4 = {};
        __builtin_amdgcn_s_setprio(1);
        t4 = MFMA16(kf[j][0], i ? bq10 : bq00, t4, 0, 0, 0);
        t4 = MFMA16(kf[j][1], i ? bq11 : bq01, t4, 0, 0, 0);
        __builtin_amdgcn_s_setprio(0);
        const bool sub_ok = (kmin + 15 <= qmin) && (qmin + 15 - kmin < 512);
        float p[4];
        if (sub_ok) {
          #pragma unroll
          for (int r = 0; r < 4; ++r) p[r] = fexp2(t4[r]);
        } else {
          int qpos = t0 + row;
          #pragma unroll
          for (int r = 0; r < 4; ++r) {
            int kpos = kmin + quad * 4 + r;       // kmin >= 16 guaranteed here
            unsigned diff = (unsigned)(qpos - kpos);
            p[r] = (diff < 512u) ? fexp2(t4[r]) : 0.f;
          }
        }
        uint2 w;
        w.x = pack_bf(p[0], p[1]);
        w.y = pack_bf(p[2], p[3]);
        *dst = w;
      }
    }
    // PV + l accumulation; V frags contiguous 1KB each, reused across i
    const u16* vp = vbase + (size_t)kb0 * 64;
    #pragma unroll
    for (int h = 0; h < 2; ++h) {
      bf16x8 bv0 = *(const bf16x8*)(vp + h * 512);
      bf16x8 bv1 = *(const bf16x8*)(vp + 1024 + h * 512);
      bf16x8 bv2 = *(const bf16x8*)(vp + 2048 + h * 512);
      bf16x8 bv3 = *(const bf16x8*)(vp + 3072 + h * 512);
      #pragma unroll
      for (int i = 0; i < 2; ++i) {
        int row = i * 16 + l16;
        int g0 = h * 8 + 2 * quad;
        uint2 r0 = *(uint2*)&ps[row * 64 + ((g0 ^ l16) & 15) * 4];
        uint2 r1 = *(uint2*)&ps[row * 64 + (((g0 + 1) ^ l16) & 15) * 4];
        union { uint4 u; bf16x8 v; } cc; cc.u = make_uint4(r0.x, r0.y, r1.x, r1.y);
        bf16x8 ap = cc.v;
        __builtin_amdgcn_s_setprio(1);
        lacc[i] = MFMA16(ap, ones, lacc[i], 0, 0, 0);
        oacc[i][0] = MFMA16(ap, bv0, oacc[i][0], 0, 0, 0);
        oacc[i][1] = MFMA16(ap, bv1, oacc[i][1], 0, 0, 0);
        oacc[i][2] = MFMA16(ap, bv2, oacc[i][2], 0, 0, 0);
        oacc[i][3] = MFMA16(ap, bv3, oacc[i][3], 0, 0, 0);
        __builtin_amdgcn_s_setprio(0);
      }
    }
  };

  for (int t = lo; t <= hi; t += 2) {
    if (t + 1 <= hi) loadK((t + 1) << 6, kb2);
    tilec(t << 6, ka);
    if (t + 1 <= hi) {
      if (t + 2 <= hi) loadK((t + 2) << 6, ka);
      tilec((t + 1) << 6, kb2);
    }
  }

  // ---- epilogue: O/l -> bf16 [B,S,H*64], granule-swizzled for GEMM3 staging ----
  const int b = bh >> 4, h = bh & 15;
  #pragma unroll
  for (int i = 0; i < 2; ++i) {
    #pragma unroll
    for (int r = 0; r < 4; ++r) {
      float inv = 1.f / lacc[i][r];
      int srow = t0 + i * 16 + quad * 4 + r;
      size_t rowoff = ((size_t)(b * 4096 + srow)) * 1024 + h * 64;
      #pragma unroll
      for (int jd = 0; jd < 4; ++jd) {
        int g = ((jd * 2 + (l16 >> 3)) ^ srow) & 7;
        ob[rowoff + (g << 3) + (l16 & 7)] = f2bf(oacc[i][jd][r] * inv);
      }
    }
  }
}

// ---------------- launch ----------------

extern "C" void kernel_launch(void* const* d_in, const int* in_sizes, int n_in,
                              void* d_out, int out_size, void* d_ws, size_t ws_size,
                              hipStream_t stream) {
  const float* x    = (const float*)d_in[0];
  const float* wqkv = (const float*)d_in[1];
  const float* wout = (const float*)d_in[2];
  float* out = (float*)d_out;

  u16* ws    = (u16*)d_ws;
  u16* xb    = ws;                                   // 8192*1024  (reused as obuf)
  u16* wqkvb = xb + (size_t)8192 * 1024;             // 3072*1024
  u16* woutb = wqkvb + (size_t)3072 * 1024;          // 1024*1024
  u16* qbuf  = woutb + (size_t)1024 * 1024;          // [2,16,4096,64]
  u16* kbuf  = qbuf + (size_t)8388608;
  u16* vbuf  = kbuf + (size_t)8388608;               // (unused now)
  u16* vtb   = vbuf + (size_t)8388608;               // operand-order V (written by gemm1)
  u16* obuf  = xb;                                   // alias: xb dead after gemm1

  cast_all_kernel<<<12288, 256, 0, stream>>>(x, wqkv, wout, ws);

  gemm_bt<1><<<dim3(24, 64), 256, 0, stream>>>(xb, wqkvb, nullptr, qbuf, kbuf, vtb,
                                               8192, 3072, 1024);
  attn_kernel<<<1024, 256, 0, stream>>>(qbuf, kbuf, vtb, obuf);
  gemm_bt<0><<<dim3(8, 64), 256, 0, stream>>>(obuf, woutb, out, nullptr, nullptr, nullptr,
                                              8192, 1024, 1024);
}

// Round 4
// 222.266 us; speedup vs baseline: 1.1664x; 1.0491x over previous
//
#include <hip/hip_runtime.h>
#include <hip/hip_bf16.h>

#define AS1 __attribute__((address_space(1)))
#define AS3 __attribute__((address_space(3)))

typedef unsigned short u16;
typedef short bf16x8 __attribute__((ext_vector_type(8)));
typedef unsigned short u16x8 __attribute__((ext_vector_type(8)));
typedef float f32x4 __attribute__((ext_vector_type(4)));

#define MFMA16 __builtin_amdgcn_mfma_f32_16x16x32_bf16

// ---------------- helpers ----------------

__device__ __forceinline__ u16 f2bf(float f) {        // RNE (finite data)
  union { float f; unsigned u; } c; c.f = f;
  unsigned u = c.u;
  u = u + 0x7fffu + ((u >> 16) & 1u);
  return (u16)(u >> 16);
}

__device__ __forceinline__ float fexp2(float x) {
#if __has_builtin(__builtin_amdgcn_exp2f)
  return __builtin_amdgcn_exp2f(x);
#else
  return exp2f(x);
#endif
}

// pack bf16(a) low16, bf16(b) high16 (truncating) — 1 v_perm_b32
__device__ __forceinline__ unsigned pack_bf(float a, float b) {
  union { float f; unsigned u; } ua, ub; ua.f = a; ub.f = b;
  return __builtin_amdgcn_perm(ub.u, ua.u, 0x07060302u);
}

__device__ __forceinline__ void gl_lds16(const void* g, void* l) {
  __builtin_amdgcn_global_load_lds((const AS1 void*)g, (AS3 void*)l, 16, 0, 0);
}

// ---------------- cast fp32 -> bf16, with 64-col-tile granule swizzle ----------------

__global__ void cast_all_kernel(const float* __restrict__ x,
                                const float* __restrict__ wqkv,
                                const float* __restrict__ wout,
                                u16* __restrict__ ws) {
  int i = blockIdx.x * blockDim.x + threadIdx.x;   // float4 index, 3145728 total
  const float4* src;
  int rel;
  size_t matbase;
  if (i < 2097152)      { src = (const float4*)x + i;                rel = i;           matbase = 0; }
  else if (i < 2883584) { src = (const float4*)wqkv + (i - 2097152); rel = i - 2097152; matbase = 8388608; }
  else                  { src = (const float4*)wout + (i - 2883584); rel = i - 2883584; matbase = 11534336; }
  float4 f = *src;
  ushort4 o;
  o.x = f2bf(f.x); o.y = f2bf(f.y); o.z = f2bf(f.z); o.w = f2bf(f.w);
  int fe  = rel * 4;
  int row = fe >> 10, c = fe & 1023;
  int newc = (c & ~63) | (((((c >> 3) ^ row) & 7) << 3)) | (c & 7);
  ((ushort4*)ws)[(matbase + (size_t)row * 1024 + newc) >> 2] = o;
}

// ---------------- GEMM: C[M,N] = A[M,K] * B[N,K]^T  (bf16 in, fp32 acc) ----------------
// Round-0 proven main loop. EPI==1: QKV epilogue; V-part blocks (bn>=2048) write V directly
// in attn operand order (pack_v fused away).

template<int EPI>
__global__ __launch_bounds__(256) void gemm_bt(
    const u16* __restrict__ A, const u16* __restrict__ Bm,
    float* __restrict__ Cf,
    u16* __restrict__ qd, u16* __restrict__ kd, u16* __restrict__ vd,
    int M, int N, int K)
{
  __shared__ u16 As[128 * 64];
  __shared__ u16 Bs[128 * 64];

  const int tid  = threadIdx.x;
  const int wave = tid >> 6, lane = tid & 63;
  const int quad = lane >> 4, l16 = lane & 15;
  const int bm = blockIdx.y * 128, bn = blockIdx.x * 128;
  const int wm = (wave >> 1) * 64, wn = (wave & 1) * 64;

  f32x4 acc[4][4] = {};

  const int srow = wave * 32 + (lane >> 3);
  const int scol = (lane & 7) * 8;

  for (int kt = 0; kt < K; kt += 64) {
    __syncthreads();
    #pragma unroll
    for (int i = 0; i < 4; ++i) {
      gl_lds16(&A[(size_t)(bm + srow + i * 8) * K + kt + scol], &As[(wave * 32 + i * 8) * 64]);
      gl_lds16(&Bm[(size_t)(bn + srow + i * 8) * K + kt + scol], &Bs[(wave * 32 + i * 8) * 64]);
    }
    __syncthreads();
    #pragma unroll
    for (int kk = 0; kk < 64; kk += 32) {
      bf16x8 af[4], bb[4];
      #pragma unroll
      for (int i = 0; i < 4; ++i) {
        int row = wm + i * 16 + l16;
        af[i] = *(const bf16x8*)&As[row * 64 + (((((kk >> 3) + quad) ^ row) & 7) << 3)];
      }
      #pragma unroll
      for (int j = 0; j < 4; ++j) {
        int row = wn + j * 16 + l16;
        bb[j] = *(const bf16x8*)&Bs[row * 64 + (((((kk >> 3) + quad) ^ row) & 7) << 3)];
      }
      #pragma unroll
      for (int i = 0; i < 4; ++i)
        #pragma unroll
        for (int j = 0; j < 4; ++j)
          acc[i][j] = MFMA16(af[i], bb[j], acc[i][j], 0, 0, 0);
    }
  }

  const int partU = bn >> 10;          // block-uniform (128 | 1024)
  if (EPI == 1 && partU == 2) {
    // ---- fused pack_v: write V straight into operand-order vt ----
    const int b = bm >> 12;
    #pragma unroll
    for (int i = 0; i < 4; ++i) {
      int s0q = (bm + wm + i * 16 + quad * 4) & 4095;
      int t  = s0q >> 6, k6 = s0q & 63;
      int h2 = k6 >> 5, q2 = (k6 >> 3) & 3, ssb = k6 & 7;
      #pragma unroll
      for (int j = 0; j < 4; ++j) {
        int nbase = bn + wn + j * 16;
        int h  = (nbase >> 6) & 15;
        int jd = (nbase & 63) >> 4;
        unsigned lo = (unsigned)f2bf(acc[i][j][0]) | ((unsigned)f2bf(acc[i][j][1]) << 16);
        unsigned hi = (unsigned)f2bf(acc[i][j][2]) | ((unsigned)f2bf(acc[i][j][3]) << 16);
        uint2 w; w.x = lo; w.y = hi;
        *(uint2*)&vd[(((size_t)(b * 16 + h)) << 18) + (size_t)t * 4096
                     + jd * 1024 + h2 * 512 + (q2 * 16 + l16) * 8 + ssb] = w;
      }
    }
  } else {
    #pragma unroll
    for (int i = 0; i < 4; ++i) {
      #pragma unroll
      for (int j = 0; j < 4; ++j) {
        #pragma unroll
        for (int r = 0; r < 4; ++r) {
          int m = bm + wm + i * 16 + quad * 4 + r;
          int n = bn + wn + j * 16 + l16;
          float val = acc[i][j][r];
          if (EPI == 0) {
            Cf[(size_t)m * N + n] = val;
          } else {
            int part = n >> 10, rem = n & 1023;
            int h = rem >> 6, d = rem & 63;
            int b = m >> 12, s = m & 4095;
            if (part == 0) val *= 0.1803368801111244f;   // 0.125 * log2(e), exp2 path
            u16* dst = (part == 0) ? qd : kd;            // part 2 handled above
            dst[((size_t)((b * 16 + h) * 4096 + s)) * 64 + d] = f2bf(val);
          }
        }
      }
    }
  }
}

// ---------------- attention: 64 queries/wave, 4 waves/block, S^T trick, coalesced V ------
// Tile-visit halving: each wave owns 64 queries (4 i-subtiles), so the ~10-tile K/V window
// sweep is amortized over 2x the queries vs the 32q/wave version. 512 blocks, 2 waves/SIMD.

__global__ __launch_bounds__(256, 2) void attn_kernel(
    const u16* __restrict__ qb, const u16* __restrict__ kb,
    const u16* __restrict__ vt, u16* __restrict__ ob)
{
  __shared__ u16 Ps[4][64 * 64];

  const int tid  = threadIdx.x;
  const int wave = tid >> 6;
  const int lane = tid & 63;
  const int quad = lane >> 4, l16 = lane & 15;
  const int bid  = blockIdx.x;
  const int bh   = bid & 31;
  const int t0   = (((bid >> 5) << 2) | wave) << 6;   // 64 queries per wave
  const size_t base = (size_t)bh << 18;
  u16* __restrict__ ps = &Ps[wave][0];

  const int l64 = l16 * 64 + quad * 8;
  const u16* vbase = vt + base + lane * 8;   // + tile*4096 + jd*1024 + h*512

  // Q B-fragments (B[n=query l16][k=dh]); q pre-scaled by 0.125*log2e
  const u16* qp = qb + base + (size_t)t0 * 64 + l64;
  bf16x8 bq[4][2];
  #pragma unroll
  for (int i = 0; i < 4; ++i) {
    bq[i][0] = *(const bf16x8*)(qp + i * 1024);
    bq[i][1] = *(const bf16x8*)(qp + i * 1024 + 32);
  }

  f32x4 oacc[4][4] = {};
  f32x4 lacc[4] = {};
  bf16x8 ones;
  #pragma unroll
  for (int s = 0; s < 8; ++s) ones[s] = (short)0x3F80;

  const int lo = max(0, t0 - 511) >> 6;
  const int hi = (t0 + 63) >> 6;

  auto loadK = [&](int kb0, bf16x8 (&kf)[4][2]) {
    #pragma unroll
    for (int j = 0; j < 4; ++j) {
      const u16* krow = kb + base + (size_t)(kb0 + j * 16) * 64 + l64;
      kf[j][0] = *(const bf16x8*)(krow);
      kf[j][1] = *(const bf16x8*)(krow + 32);
    }
  };

  bf16x8 ka[4][2], kb2[4][2];

  // ======== prefix tile (keys 0..15 causal; keys 16..31 zero-filled) ========
  {
    const u16* kpre = kb + base + l64;
    bf16x8 pk0 = *(const bf16x8*)(kpre);
    bf16x8 pk1 = *(const bf16x8*)(kpre + 32);
    loadK(lo << 6, ka);                        // prefetch first window tile
    bf16x8 pv[4];
    #pragma unroll
    for (int jd = 0; jd < 4; ++jd)
      pv[jd] = *(const bf16x8*)(vbase + jd * 1024);   // tile 0, h=0

    #pragma unroll
    for (int i = 0; i < 4; ++i) {
      f32x4 t4 = {};
      t4 = MFMA16(pk0, bq[i][0], t4, 0, 0, 0);
      t4 = MFMA16(pk1, bq[i][1], t4, 0, 0, 0);
      int row = i * 16 + l16;
      int qpos = t0 + row;
      float p[4];
      #pragma unroll
      for (int r = 0; r < 4; ++r) {
        int kpos = quad * 4 + r;
        p[r] = (kpos <= qpos) ? fexp2(t4[r]) : 0.f;
      }
      uint2 w;
      w.x = pack_bf(p[0], p[1]);
      w.y = pack_bf(p[2], p[3]);
      *(uint2*)&ps[row * 64 + ((quad ^ l16) & 15) * 4] = w;
      uint2 z; z.x = 0u; z.y = 0u;
      *(uint2*)&ps[row * 64 + (((4 + quad) ^ l16) & 15) * 4] = z;
    }
    #pragma unroll
    for (int i = 0; i < 4; ++i) {
      int row = i * 16 + l16;
      uint2 r0 = *(uint2*)&ps[row * 64 + (((2 * quad) ^ l16) & 15) * 4];
      uint2 r1 = *(uint2*)&ps[row * 64 + (((2 * quad + 1) ^ l16) & 15) * 4];
      union { uint4 u; bf16x8 v; } cc; cc.u = make_uint4(r0.x, r0.y, r1.x, r1.y);
      bf16x8 ap = cc.v;
      __builtin_amdgcn_s_setprio(1);
      lacc[i] = MFMA16(ap, ones, lacc[i], 0, 0, 0);
      #pragma unroll
      for (int jd = 0; jd < 4; ++jd)
        oacc[i][jd] = MFMA16(ap, pv[jd], oacc[i][jd], 0, 0, 0);
      __builtin_amdgcn_s_setprio(0);
    }
  }

  // ======== sliding-window tiles ========
  auto tilec = [&](int kb0, bf16x8 (&kf)[4][2]) {
    #pragma unroll
    for (int j = 0; j < 4; ++j) {
      const int kmin = kb0 + j * 16;
      #pragma unroll
      for (int i = 0; i < 4; ++i) {
        const int qmin = t0 + i * 16;
        const int row  = i * 16 + l16;
        uint2* dst = (uint2*)&ps[row * 64 + (((j * 4 + quad) ^ l16) & 15) * 4];
        // wave-uniform subtile classification
        const bool sub_masked = (kmin > qmin + 15) || (qmin - kmin >= 527) || (kmin < 16);
        if (sub_masked) { uint2 z; z.x = 0u; z.y = 0u; *dst = z; continue; }
        f32x4 t4 = {};
        __builtin_amdgcn_s_setprio(1);
        t4 = MFMA16(kf[j][0], bq[i][0], t4, 0, 0, 0);
        t4 = MFMA16(kf[j][1], bq[i][1], t4, 0, 0, 0);
        __builtin_amdgcn_s_setprio(0);
        const bool sub_ok = (kmin + 15 <= qmin) && (qmin + 15 - kmin < 512);
        float p[4];
        if (sub_ok) {
          #pragma unroll
          for (int r = 0; r < 4; ++r) p[r] = fexp2(t4[r]);
        } else {
          int qpos = t0 + row;
          #pragma unroll
          for (int r = 0; r < 4; ++r) {
            int kpos = kmin + quad * 4 + r;       // kmin >= 16 guaranteed here
            unsigned diff = (unsigned)(qpos - kpos);
            p[r] = (diff < 512u) ? fexp2(t4[r]) : 0.f;
          }
        }
        uint2 w;
        w.x = pack_bf(p[0], p[1]);
        w.y = pack_bf(p[2], p[3]);
        *dst = w;
      }
    }
    // PV + l accumulation; V frags contiguous 1KB each, reused across i
    const u16* vp = vbase + (size_t)kb0 * 64;
    #pragma unroll
    for (int h = 0; h < 2; ++h) {
      bf16x8 bv0 = *(const bf16x8*)(vp + h * 512);
      bf16x8 bv1 = *(const bf16x8*)(vp + 1024 + h * 512);
      bf16x8 bv2 = *(const bf16x8*)(vp + 2048 + h * 512);
      bf16x8 bv3 = *(const bf16x8*)(vp + 3072 + h * 512);
      #pragma unroll
      for (int i = 0; i < 4; ++i) {
        int row = i * 16 + l16;
        int g0 = h * 8 + 2 * quad;
        uint2 r0 = *(uint2*)&ps[row * 64 + ((g0 ^ l16) & 15) * 4];
        uint2 r1 = *(uint2*)&ps[row * 64 + (((g0 + 1) ^ l16) & 15) * 4];
        union { uint4 u; bf16x8 v; } cc; cc.u = make_uint4(r0.x, r0.y, r1.x, r1.y);
        bf16x8 ap = cc.v;
        __builtin_amdgcn_s_setprio(1);
        lacc[i] = MFMA16(ap, ones, lacc[i], 0, 0, 0);
        oacc[i][0] = MFMA16(ap, bv0, oacc[i][0], 0, 0, 0);
        oacc[i][1] = MFMA16(ap, bv1, oacc[i][1], 0, 0, 0);
        oacc[i][2] = MFMA16(ap, bv2, oacc[i][2], 0, 0, 0);
        oacc[i][3] = MFMA16(ap, bv3, oacc[i][3], 0, 0, 0);
        __builtin_amdgcn_s_setprio(0);
      }
    }
  };

  for (int t = lo; t <= hi; t += 2) {
    if (t + 1 <= hi) loadK((t + 1) << 6, kb2);
    tilec(t << 6, ka);
    if (t + 1 <= hi) {
      if (t + 2 <= hi) loadK((t + 2) << 6, ka);
      tilec((t + 1) << 6, kb2);
    }
  }

  // ---- epilogue: O/l -> bf16 [B,S,H*64], granule-swizzled for GEMM3 staging ----
  const int b = bh >> 4, h = bh & 15;
  #pragma unroll
  for (int i = 0; i < 4; ++i) {
    #pragma unroll
    for (int r = 0; r < 4; ++r) {
      float inv = 1.f / lacc[i][r];
      int srow = t0 + i * 16 + quad * 4 + r;
      size_t rowoff = ((size_t)(b * 4096 + srow)) * 1024 + h * 64;
      #pragma unroll
      for (int jd = 0; jd < 4; ++jd) {
        int g = ((jd * 2 + (l16 >> 3)) ^ srow) & 7;
        ob[rowoff + (g << 3) + (l16 & 7)] = f2bf(oacc[i][jd][r] * inv);
      }
    }
  }
}

// ---------------- launch ----------------

extern "C" void kernel_launch(void* const* d_in, const int* in_sizes, int n_in,
                              void* d_out, int out_size, void* d_ws, size_t ws_size,
                              hipStream_t stream) {
  const float* x    = (const float*)d_in[0];
  const float* wqkv = (const float*)d_in[1];
  const float* wout = (const float*)d_in[2];
  float* out = (float*)d_out;

  u16* ws    = (u16*)d_ws;
  u16* xb    = ws;                                   // 8192*1024  (reused as obuf)
  u16* wqkvb = xb + (size_t)8192 * 1024;             // 3072*1024
  u16* woutb = wqkvb + (size_t)3072 * 1024;          // 1024*1024
  u16* qbuf  = woutb + (size_t)1024 * 1024;          // [2,16,4096,64]
  u16* kbuf  = qbuf + (size_t)8388608;
  u16* vbuf  = kbuf + (size_t)8388608;               // (unused now)
  u16* vtb   = vbuf + (size_t)8388608;               // operand-order V (written by gemm1)
  u16* obuf  = xb;                                   // alias: xb dead after gemm1

  cast_all_kernel<<<12288, 256, 0, stream>>>(x, wqkv, wout, ws);

  gemm_bt<1><<<dim3(24, 64), 256, 0, stream>>>(xb, wqkvb, nullptr, qbuf, kbuf, vtb,
                                               8192, 3072, 1024);
  attn_kernel<<<512, 256, 0, stream>>>(qbuf, kbuf, vtb, obuf);
  gemm_bt<0><<<dim3(8, 64), 256, 0, stream>>>(obuf, woutb, out, nullptr, nullptr, nullptr,
                                              8192, 1024, 1024);
}